// Round 3
// baseline (87.406 us; speedup 1.0000x reference)
//
#include <hip/hip_runtime.h>
#include <math.h>

// RGate on 22 qubits: y = (⊗_i exp(-0.5i*angle[i]*sigma_x)) x
//   x:     float32[2^22]  (d_in[0])
//   angle: float32[22]    (d_in[1])
//   out:   float32[2^22]  (d_out) = REAL part of final complex state.
// Site n acts on global bit b = 21-n; gate on bit b uses angle[21-b] = csb[12-b]
// (pass 1, csb[j] = angle[9+j]) / csb[b-13... ] (pass 2, csb[j] = angle[j]).
// Butterfly (M = [[c,-is],[-is,c]], symmetric):
//   a' = (c*ar + s*bi, c*ai - s*br);  b' = (c*br + s*ai, c*bi - s*ar)
// Side-symmetric cross-lane form (same formula both sides, p = partner):
//   v' = (c*v.x + s*p.y, c*v.y - s*p.x)
//
// R2: pass-1 phase count 5 -> 3. Theory: passes are block-critical-path bound
// (2 blocks/CU, no block pipelining; barriers + LDS round-trips dominate, not
// BW). New round-C map e = (k&3) | (t>>3)<<2 | (t&7)<<8 | (k>>2)<<11 puts
// gate bits 8..10 on LANE bits 0..2 (shfl_xor butterflies), bits 11..12 on k
// bits 2..3 (register pairs), bits 0..1 on k bits 0..1 -> thread's 4-element
// k-groups are CONTIGUOUS -> pack to uint4 in registers and store straight to
// global (each wave-store = 8 full 128-B lines). Deletes the pack LDS round:
// -2 barriers, -16 b32 LDS writes, -4 b128 LDS reads; C-read 16xb64 -> 8xb128.
// Pass 2 unchanged (attribution). Numerics bit-identical -> absmax 0.015625.
//
// Pass 1: bits 0..12 (angles 21..9), x -> packed-bf16 complex mid (in d_out).
// Pass 2: bits 13..21 (angles 8..0), mid -> f32 real parts, in place in d_out.
// d_ws unused (R0: 256-MiB poison fill is timed unconditionally regardless).

static __device__ __forceinline__ float bf2f(unsigned short u) {
    return __uint_as_float(((unsigned int)u) << 16);
}
static __device__ __forceinline__ unsigned short f2bf(float f) {
    unsigned int x = __float_as_uint(f);
    x += 0x7FFFu + ((x >> 16) & 1u);          // round-to-nearest-even
    return (unsigned short)(x >> 16);
}
static __device__ __forceinline__ unsigned int packc(float2 v) {
    return (unsigned int)f2bf(v.x) | ((unsigned int)f2bf(v.y) << 16);
}
static __device__ __forceinline__ float2 unpackc(unsigned int u) {
    return make_float2(bf2f((unsigned short)(u & 0xFFFFu)),
                       bf2f((unsigned short)(u >> 16)));
}

static __device__ __forceinline__ void bfly(float2& a, float2& b, float c, float s) {
    float ar = a.x, ai = a.y, br = b.x, bi = b.y;
    a.x = fmaf(c, ar,  s * bi);
    a.y = fmaf(c, ai, -s * br);
    b.x = fmaf(c, br,  s * ai);
    b.y = fmaf(c, bi, -s * ar);
}

// LDS swizzle at float4 granularity (preserves float2-pair adjacency for b128):
// float4 slot f -> f ^ ((f>>3)&7). All b64/b128 phases below are at the
// structural bank floor (enumerated per-round in comments).
static __device__ __forceinline__ unsigned swf(unsigned f) {
    return f ^ ((f >> 3) & 7u);
}
// float2-unit address e -> swizzled float2 address.
static __device__ __forceinline__ unsigned swe(unsigned e) {
    return (swf(e >> 1) << 1) | (e & 1u);
}

// ---------------- Pass 1: global bits 0..12 (angles 21..9) ----------------
// 512 blocks x 512 threads; tile = 8192 contiguous complex (64 KB LDS f32).
// Phases: A = bits 0..3 (from global, b128 LDS store), barrier, B = bits 4..7
// (b64 LDS rw), barrier, C = bits 11..12 (k pairs) + 8..10 (shfl_xor 1/2/4)
// + bf16 pack + DIRECT uint4 global store. 3 barriers total (incl. csb init).
__global__ __launch_bounds__(512) void rgate_pass1(
    const float* __restrict__ x, const float* __restrict__ ang,
    unsigned int* __restrict__ mid)
{
    __shared__ __align__(16) float2 tile[8192];
    __shared__ float2 csb[13];                    // csb[j] = (cos,sin)(angle[9+j]/2)
    float4* t4 = (float4*)tile;
    const unsigned t = threadIdx.x;
    if (t < 13) {
        float s, c; sincosf(0.5f * ang[9 + t], &s, &c);
        csb[t] = make_float2(c, s);
    }
    __syncthreads();

    const unsigned base = (unsigned)blockIdx.x << 13;
    float2 v[16];

    // Round A: thread owns 16 CONSECUTIVE elements e = t*16+k -> 4 float4 loads
    // (64 B/lane, wave reads 4 KB contiguous). Gates bits 0..3 = csb[12-j].
    {
        const float4* x4 = (const float4*)(x + base);
        #pragma unroll
        for (int q = 0; q < 4; ++q) {
            const float4 f = x4[(t << 2) + (unsigned)q];
            v[4*q+0] = make_float2(f.x, 0.0f);
            v[4*q+1] = make_float2(f.y, 0.0f);
            v[4*q+2] = make_float2(f.z, 0.0f);
            v[4*q+3] = make_float2(f.w, 0.0f);
        }
    }
    #pragma unroll
    for (int j = 0; j < 4; ++j) {
        const float2 g = csb[12 - j];
        const int m = 1 << j;
        #pragma unroll
        for (int k = 0; k < 16; ++k)
            if (!(k & m)) bfly(v[k], v[k | m], g.x, g.y);
    }
    // b128 stores, slots f = t*8+q; swf spreads q across bank groups (floor).
    #pragma unroll
    for (int q = 0; q < 8; ++q) {
        const unsigned f = (t << 3) + (unsigned)q;
        t4[swf(f)] = make_float4(v[2*q].x, v[2*q].y, v[2*q+1].x, v[2*q+1].y);
    }
    __syncthreads();

    // Round B: e = lo + k*16 + hi*256 (lo = t&15 -> bits 0..3, k -> 4..7,
    // hi = t>>4 in 0..31 -> bits 8..12). Gates bits 4..7 = csb[8-j].
    {
        const unsigned lo = t & 15u, hi = t >> 4;
        #pragma unroll
        for (int k = 0; k < 16; ++k)
            v[k] = tile[swe(lo + ((unsigned)k << 4) + (hi << 8))];
        #pragma unroll
        for (int j = 0; j < 4; ++j) {
            const float2 g = csb[8 - j];
            const int m = 1 << j;
            #pragma unroll
            for (int k = 0; k < 16; ++k)
                if (!(k & m)) bfly(v[k], v[k | m], g.x, g.y);
        }
        #pragma unroll
        for (int k = 0; k < 16; ++k)
            tile[swe(lo + ((unsigned)k << 4) + (hi << 8))] = v[k];
    }
    __syncthreads();

    // Round C: e = (k&3) | (t>>3)<<2 | (t&7)<<8 | (k>>2)<<11 (bijective:
    // e{0..1}<-k{0..1}, e{2..7}<-t{3..8}, e{8..10}<-t{0..2}=LANE{0..2},
    // e{11..12}<-k{2..3}). Read 2xb128 per k-group (4 consecutive e).
    // Bank: f bits {0=b,1..3=l3..l5,4..6=w,7..9=l0..l2,10..11=g}; swf group =
    // [b^l5, l3^w0, l4^w1] -> 8 lanes/group, distinct rows = b128 floor.
    {
        const unsigned cb = ((t >> 3) << 1) | ((t & 7u) << 7);   // f-base
        #pragma unroll
        for (int g = 0; g < 4; ++g) {
            const unsigned f0 = cb | ((unsigned)g << 10);
            const float4 r0 = t4[swf(f0)];
            const float4 r1 = t4[swf(f0 | 1u)];
            v[4*g+0] = make_float2(r0.x, r0.y);
            v[4*g+1] = make_float2(r0.z, r0.w);
            v[4*g+2] = make_float2(r1.x, r1.y);
            v[4*g+3] = make_float2(r1.z, r1.w);
        }
    }
    // Gates bits 11 (csb[1], m=4) and 12 (csb[0], m=8): register pairs.
    {
        const float2 g1 = csb[1];
        #pragma unroll
        for (int k = 0; k < 16; ++k)
            if (!(k & 4)) bfly(v[k], v[k | 4], g1.x, g1.y);
        const float2 g0 = csb[0];
        #pragma unroll
        for (int k = 0; k < 16; ++k)
            if (!(k & 8)) bfly(v[k], v[k | 8], g0.x, g0.y);
    }
    // Gates bits 8,9,10 = csb[4],csb[3],csb[2] via shfl_xor(1/2/4): partner's
    // (re,im) pulled cross-lane; side-symmetric form, no divergence. Numerics
    // identical to the paired bfly (same fmaf structure per element).
    {
        const float2 ga = csb[4];
        #pragma unroll
        for (int k = 0; k < 16; ++k) {
            const float px = __shfl_xor(v[k].x, 1);
            const float py = __shfl_xor(v[k].y, 1);
            v[k] = make_float2(fmaf(ga.x, v[k].x,  ga.y * py),
                               fmaf(ga.x, v[k].y, -ga.y * px));
        }
        const float2 gb = csb[3];
        #pragma unroll
        for (int k = 0; k < 16; ++k) {
            const float px = __shfl_xor(v[k].x, 2);
            const float py = __shfl_xor(v[k].y, 2);
            v[k] = make_float2(fmaf(gb.x, v[k].x,  gb.y * py),
                               fmaf(gb.x, v[k].y, -gb.y * px));
        }
        const float2 gc = csb[2];
        #pragma unroll
        for (int k = 0; k < 16; ++k) {
            const float px = __shfl_xor(v[k].x, 4);
            const float py = __shfl_xor(v[k].y, 4);
            v[k] = make_float2(fmaf(gc.x, v[k].x,  gc.y * py),
                               fmaf(gc.x, v[k].y, -gc.y * px));
        }
    }
    // Pack each 4-element k-group to one uint4, store direct to global.
    // Wave-store (fixed w,g): 8 clusters of 8 consecutive uint4 = 8 full
    // 128-B lines; all lines fully written across waves/groups.
    {
        uint4* m4 = (uint4*)(mid + base);
        const unsigned ob = (t >> 3) | ((t & 7u) << 6);
        #pragma unroll
        for (int g = 0; g < 4; ++g) {
            uint4 u;
            u.x = packc(v[4*g+0]);
            u.y = packc(v[4*g+1]);
            u.z = packc(v[4*g+2]);
            u.w = packc(v[4*g+3]);
            m4[ob | ((unsigned)g << 9)] = u;
        }
    }
}

// ---------------- Pass 2: global bits 13..21 (angles 8..0) ----------------
// 512 blocks x 512 threads. l = bits 0..3 (16 contiguous complex = 64-B
// granule), h = bits 13..21 (512 values); blk covers bits 4..12. Tile = 8192
// complex (64 KB f32), logical e = h*16 + l, stored at swe(e).
// Global element g = (h<<13)|(blk<<4)|l. XCD remap: 64 consecutive logical
// blks per XCD so adjacent 64-B granules share 128-B L2 lines.
// IN-PLACE in d_out: block's read bytes (uint2 x8 per h) == write bytes
// (f32 x16 per h); reads drain at the first barrier before any write;
// byte sets partitioned by blk across blocks. No __restrict__ (aliasing).
__global__ __launch_bounds__(512) void rgate_pass2(
    const unsigned int* mid, const float* __restrict__ ang,
    float* outr)   // same buffer as mid (d_out), different interpretation
{
    __shared__ __align__(16) float2 tile[8192];
    __shared__ float2 csb[9];                     // csb[j] = (cos,sin)(angle[j]/2)
    float4* t4 = (float4*)tile;
    const unsigned t = threadIdx.x;
    if (t < 9) {
        float s, c; sincosf(0.5f * ang[t], &s, &c);
        csb[t] = make_float2(c, s);
    }
    __syncthreads();

    const unsigned p = blockIdx.x;
    const unsigned blk = ((p & 7u) << 6) | (p >> 3);   // XCD-grouped logical blk
    const uint2* g2 = (const uint2*)mid;               // 1 uint2 = 2 packed complex
    float2 v[16];
    const unsigned tl = t & 7u;                        // l-pair index (l = 2*tl)
    const unsigned th = t >> 3;                        // h bits 3..8

    // Round A: k covers h bits 0..2 (global 13..15, angles 8..6 = csb[8-j]).
    // Read: 8 lanes x uint2 = 64 B contiguous per (blk,h) -> full-line granules.
    {
        #pragma unroll
        for (int k = 0; k < 8; ++k) {
            const unsigned h = (th << 3) | (unsigned)k;
            const uint2 u = g2[(h << 12) + (blk << 3) + tl];
            v[2*k]   = unpackc(u.x);
            v[2*k+1] = unpackc(u.y);
        }
        #pragma unroll
        for (int j = 0; j < 3; ++j) {
            const float2 g = csb[8 - j];
            const int m = 2 << j;                      // v-index bits 1..3 = h bits 0..2
            #pragma unroll
            for (int k = 0; k < 16; ++k)
                if (!(k & m)) bfly(v[k], v[k | m], g.x, g.y);
        }
        #pragma unroll
        for (int k = 0; k < 8; ++k) {
            const unsigned h = (th << 3) | (unsigned)k;
            const unsigned f = (h << 3) + tl;          // float4 slot of e=(h<<4)+2*tl
            t4[swf(f)] = make_float4(v[2*k].x, v[2*k].y, v[2*k+1].x, v[2*k+1].y);
        }
    }
    __syncthreads();   // also drains all round-A global reads (in-place safety)

    // Round B: k covers h bits 3..6 (global 16..19, angles 5..2 = csb[5-j]).
    // e = (t&127) -> bits 0..6, k -> bits 7..10, (t>>7) -> bits 11..12.
    {
        const unsigned abase = (t & 127u) + ((t >> 7) << 11);
        #pragma unroll
        for (int k = 0; k < 16; ++k)
            v[k] = tile[swe(abase + ((unsigned)k << 7))];
        #pragma unroll
        for (int j = 0; j < 4; ++j) {
            const float2 g = csb[5 - j];
            const int m = 1 << j;
            #pragma unroll
            for (int k = 0; k < 16; ++k)
                if (!(k & m)) bfly(v[k], v[k | m], g.x, g.y);
        }
        #pragma unroll
        for (int k = 0; k < 16; ++k)
            tile[swe(abase + ((unsigned)k << 7))] = v[k];
    }
    __syncthreads();

    // Round C: e = t + k*512 (t -> bits 0..8, k -> bits 9..12). Gates h bits
    // 7..8 = e bits 11..12 (global 20..21, angles 1..0): m = 4 -> csb[1],
    // m = 8 -> csb[0]. k bits 0..1 (h bits 5..6, already done) ride along.
    {
        #pragma unroll
        for (int k = 0; k < 16; ++k)
            v[k] = tile[swe(t + ((unsigned)k << 9))];
        {
            const float2 g1 = csb[1];
            #pragma unroll
            for (int k = 0; k < 16; ++k)
                if (!(k & 4)) bfly(v[k], v[k | 4], g1.x, g1.y);
            const float2 g0 = csb[0];
            #pragma unroll
            for (int k = 0; k < 16; ++k)
                if (!(k & 8)) bfly(v[k], v[k | 8], g0.x, g0.y);
        }
        // f32 REAL parts. Per wave per k: 4 groups of 16 consecutive floats
        // = 64-B write granules (same bytes we read in round A -> in-place OK).
        #pragma unroll
        for (int k = 0; k < 16; ++k) {
            const unsigned e = t + ((unsigned)k << 9);
            outr[((e >> 4) << 13) + (blk << 4) + (e & 15u)] = v[k].x;
        }
    }
}

extern "C" void kernel_launch(void* const* d_in, const int* in_sizes, int n_in,
                              void* d_out, int out_size, void* d_ws, size_t ws_size,
                              hipStream_t stream) {
    (void)in_sizes; (void)n_in; (void)out_size; (void)d_ws; (void)ws_size;
    const float* x   = (const float*)d_in[0];   // float32[2^22]
    const float* ang = (const float*)d_in[1];   // float32[22]

    // d_ws deliberately UNUSED (R0: fill is timed unconditionally; not our tax
    // to avoid, but keeping footprint at 32 MB helps L2/L3 residency).
    unsigned int* mid = (unsigned int*)d_out;
    float* outr = (float*)d_out;

    rgate_pass1<<<512, 512, 0, stream>>>(x, ang, mid);
    rgate_pass2<<<512, 512, 0, stream>>>(mid, ang, outr);
}